// Round 1
// 451.898 us; speedup vs baseline: 1.0658x; 1.0658x over previous
//
#include <hip/hip_runtime.h>

typedef unsigned short u16;
typedef unsigned int u32;
typedef __bf16 bf16_t;
typedef bf16_t bf16x8 __attribute__((ext_vector_type(8)));
typedef float floatx4 __attribute__((ext_vector_type(4)));

__device__ __forceinline__ float bf2f(u16 h) {
    union { unsigned u; float f; } v;
    v.u = ((unsigned)h) << 16;
    return v.f;
}

__device__ __forceinline__ u16 f2bf(float f) {
    union { float f; unsigned u; } v;
    v.f = f;
    unsigned r = v.u + 0x7fffu + ((v.u >> 16) & 1u);
    return (u16)(r >> 16);
}

// async global->LDS, 16B per lane. LDS dest = uniform base + lane*16 (HW rule).
typedef __attribute__((address_space(1))) const u32 gu32;
typedef __attribute__((address_space(3))) u32 lu32;
__device__ __forceinline__ void gload16(const void* g, void* l) {
    __builtin_amdgcn_global_load_lds((gu32*)g, (lu32*)l, 16, 0, 0);
}

// ---------------------------------------------------------------------------
// Weight transposes: fp32 in -> bf16 transposed out (tiny, L2-resident)
// ---------------------------------------------------------------------------
__global__ void transpose_one(const float* __restrict__ W, u16* __restrict__ Wt,
                              int K, int N) {
    int idx = blockIdx.x * 256 + threadIdx.x;
    if (idx >= K * N) return;
    int nrow = idx / K;
    int k = idx - nrow * K;
    Wt[idx] = f2bf(W[k * N + nrow]);   // Wt[n][k] = W[k][n]
}

// WkvT [1024][768]: rows 0..511 = Wk^T, rows 512..1023 = Wv^T
__global__ void transpose_kv(const float* __restrict__ Wk, const float* __restrict__ Wv,
                             u16* __restrict__ Wt) {
    int idx = blockIdx.x * 256 + threadIdx.x;
    if (idx >= 1024 * 768) return;
    int nrow = idx / 768;
    int k = idx - nrow * 768;
    Wt[idx] = f2bf((nrow < 512) ? Wk[k * 512 + nrow] : Wv[k * 512 + (nrow - 512)]);
}

// ---------------------------------------------------------------------------
// GEMM: C[M,N] = A[M,K] * Bt[N,K]^T (+bias), bf16 MFMA, fp32 accum.
// m97 structure: global_load_lds width-16 staging, linear LDS, 2-barrier loop.
// A fp32 case: A staged as fp32 in LDS, converted to bf16 at fragment read.
// 1D grid, XCD-aware swizzle, N-tiles innermost for A-panel L2 reuse.
// Requires: gridDim.x % 8 == 0, K % 32 == 0, N % 128 == 0.
// ---------------------------------------------------------------------------
#define TM 128
#define TN 128
#define TK 32

template <bool A_F32, bool OUT_F32>
__global__ __launch_bounds__(256) void gemm_bt(
    const void* __restrict__ A_, const u16* __restrict__ Bt,
    void* __restrict__ C_, const float* __restrict__ bias,
    int M, int K, int N, int ntl2)   // ntl2 = log2(# N tiles)
{
    constexpr int ABYTES = A_F32 ? TM * TK * 4 : TM * TK * 2;
    __shared__ __align__(16) char smem[ABYTES + TN * TK * 2];
    float* Asf = (float*)smem;                 // fp32 A tile [128][32]
    u16*   Asb = (u16*)smem;                   // bf16 A tile [128][32]
    u16*   Bs  = (u16*)(smem + ABYTES);        // bf16 B tile [128][32]

    const int tid  = threadIdx.x;
    const int lane = tid & 63;
    const int wave = tid >> 6;
    const int quad = lane >> 4;
    const int l16  = lane & 15;
    const int wm   = (wave & 1) * 64;
    const int wn   = (wave >> 1) * 64;

    // XCD-aware bijective swizzle (nwg % 8 == 0), N-tile fastest within XCD.
    const int nwg = gridDim.x;
    const int wg  = blockIdx.x;
    const int t   = (wg & 7) * (nwg >> 3) + (wg >> 3);
    const long bm = (long)(t >> ntl2) * TM;
    const long bn = (long)(t & ((1 << ntl2) - 1)) * TN;

    const float* Af = (const float*)A_;
    const u16*   Ab = (const u16*)A_;

    floatx4 acc[4][4] = {};

    for (int k0 = 0; k0 < K; k0 += TK) {
        // ---- stage B: 128x32 bf16 = 512 chunks of 16B, 2 issues/thread ----
        #pragma unroll
        for (int p = 0; p < 2; ++p) {
            int ch  = p * 256 + tid;
            int row = ch >> 2;           // 4 chunks per 64B row
            int pc  = ch & 3;
            gload16(Bt + (bn + row) * K + k0 + pc * 8,
                    Bs + (p * 256 + wave * 64) * 8);
        }
        // ---- stage A ----
        if (A_F32) {
            #pragma unroll
            for (int p = 0; p < 4; ++p) {
                int ch  = p * 256 + tid;
                int row = ch >> 3;       // 8 chunks per 128B row
                int pc  = ch & 7;
                long gr = bm + row;
                if (gr < M)
                    gload16(Af + gr * K + k0 + pc * 4,
                            Asf + (p * 256 + wave * 64) * 4);
            }
        } else {
            #pragma unroll
            for (int p = 0; p < 2; ++p) {
                int ch  = p * 256 + tid;
                int row = ch >> 2;
                int pc  = ch & 3;
                long gr = bm + row;
                if (gr < M)
                    gload16(Ab + gr * K + k0 + pc * 8,
                            Asb + (p * 256 + wave * 64) * 8);
            }
        }
        __syncthreads();   // compiler emits vmcnt(0) drain -> LDS tiles ready

        bf16x8 af[4], bfr[4];
        #pragma unroll
        for (int i = 0; i < 4; ++i) {
            int row = wm + i * 16 + l16;
            if (A_F32) {
                const float* ap = Asf + row * 32 + quad * 8;
                float4 f0 = *(const float4*)ap;
                float4 f1 = *(const float4*)(ap + 4);
                union { u16 h[8]; bf16x8 v; } pk;
                pk.h[0] = f2bf(f0.x); pk.h[1] = f2bf(f0.y);
                pk.h[2] = f2bf(f0.z); pk.h[3] = f2bf(f0.w);
                pk.h[4] = f2bf(f1.x); pk.h[5] = f2bf(f1.y);
                pk.h[6] = f2bf(f1.z); pk.h[7] = f2bf(f1.w);
                af[i] = pk.v;
            } else {
                af[i] = *(const bf16x8*)(Asb + row * 32 + quad * 8);
            }
        }
        #pragma unroll
        for (int j = 0; j < 4; ++j)
            bfr[j] = *(const bf16x8*)(Bs + (wn + j * 16 + l16) * 32 + quad * 8);
        #pragma unroll
        for (int i = 0; i < 4; ++i)
            #pragma unroll
            for (int j = 0; j < 4; ++j)
                acc[i][j] = __builtin_amdgcn_mfma_f32_16x16x32_bf16(
                    af[i], bfr[j], acc[i][j], 0, 0, 0);
        __syncthreads();   // protect LDS before next iteration's staging
    }

    #pragma unroll
    for (int i = 0; i < 4; ++i) {
        #pragma unroll
        for (int r = 0; r < 4; ++r) {
            long row = bm + wm + i * 16 + quad * 4 + r;
            if (row >= M) continue;
            #pragma unroll
            for (int j = 0; j < 4; ++j) {
                long col = bn + wn + j * 16 + l16;
                float val = acc[i][j][r];
                if (bias) val += bias[col];
                if (OUT_F32) ((float*)C_)[row * N + col] = val;
                else         ((u16*)C_)[row * N + col] = f2bf(val);
            }
        }
    }
}

// ---------------------------------------------------------------------------
// Fused attention v2 (unchanged this round — next optimization target).
// Grid (qc=16, h=8, n=16); block = 256 q-rows of one (n,h), processed as 2
// tiles of 128. k/v staged ONCE per block; V^T built by coalesced load +
// LDS->LDS transpose; softmax entirely in registers via __shfl_xor; q-tile
// and P share one LDS buffer. In-place safe.
// ---------------------------------------------------------------------------
__global__ __launch_bounds__(256) void attn_kernel(
    const u16* __restrict__ qb,   // [N, 4096, 512] bf16
    const u16* __restrict__ kvb,  // [N*77, 1024] bf16 (cols 0..511 k, 512.. v)
    u16* __restrict__ ob)         // [N, 4096, 512] bf16
{
    const int QL = 4096, HS = 512;
    const int q0 = blockIdx.x * 256;
    const int h  = blockIdx.y;
    const int n  = blockIdx.z;

    __shared__ u16 sQP[128 * 104];  // q tile (stride 72) / P (stride 104): 26.6 KB
    __shared__ u16 ks [80 * 72];    // k [c][s], c zero-padded to 80: 11.5 KB
    __shared__ u16 vts[64 * 104];   // V^T [s][c], c zero-padded to 96: 13.3 KB

    const int tid  = threadIdx.x;
    const int lane = tid & 63;
    const int wave = tid >> 6;
    const int quad = lane >> 4;
    const int l16  = lane & 15;
    const int wm   = wave * 32;     // wave's q-row offset within 128-tile

    // ---- stage k rows (coalesced, zero-pad c>=77) ----
    const u16* kbase = kvb + (long)n * 77 * 1024 + h * 64;
    for (int v = tid; v < 640; v += 256) {
        int c = v >> 3, g = (v & 7) * 8;
        uint4 val = make_uint4(0, 0, 0, 0);
        if (c < 77) val = *(const uint4*)(kbase + (long)c * 1024 + g);
        *(uint4*)(&ks[c * 72 + g]) = val;
    }
    // ---- stage v rows coalesced into sQP scratch [c][s] stride 64 ----
    const u16* vbase = kvb + (long)n * 77 * 1024 + 512 + h * 64;
    for (int v = tid; v < 616; v += 256) {          // 77 rows x 8 uint4
        int c = v >> 3, g = (v & 7) * 8;
        *(uint4*)(&sQP[c * 64 + g]) = *(const uint4*)(vbase + (long)c * 1024 + g);
    }
    __syncthreads();
    // ---- LDS->LDS transpose into vts[s][c] (zero c>=77) ----
    for (int e = tid; e < 64 * 96; e += 256) {
        int c = e >> 6, s = e & 63;                 // lanes: s fastest (reads conflict-free)
        u16 val = (c < 77) ? sQP[c * 64 + s] : (u16)0;
        vts[s * 104 + c] = val;
    }
    __syncthreads();

    const bool v4ok = (l16 < 13);   // j=4 -> c = 64+l16, valid iff c<77

    for (int it = 0; it < 2; ++it) {
        const long qrow0 = (long)q0 + it * 128;
        const u16* qbase = qb + ((long)n * QL + qrow0) * HS + h * 64;
        u16*       obase = ob + ((long)n * QL + qrow0) * HS + h * 64;

        // ---- stage q tile 128x64 (stride 72) ----
        #pragma unroll
        for (int p = 0; p < 4; ++p) {
            int v = tid + p * 256;
            int r = v >> 3, g = (v & 7) * 8;
            *(uint4*)(&sQP[r * 72 + g]) = *(const uint4*)(qbase + (long)r * HS + g);
        }
        __syncthreads();

        // ---- QK^T: wave covers rows wm..wm+31 (2 row-tiles x 5 col-tiles) ----
        floatx4 accS[2][5] = {};
        #pragma unroll
        for (int kk = 0; kk < 2; ++kk) {
            bf16x8 aq[2], bk[5];
            #pragma unroll
            for (int t = 0; t < 2; ++t)
                aq[t] = *(const bf16x8*)(&sQP[(wm + t * 16 + l16) * 72 + kk * 32 + quad * 8]);
            #pragma unroll
            for (int j = 0; j < 5; ++j)
                bk[j] = *(const bf16x8*)(&ks[(j * 16 + l16) * 72 + kk * 32 + quad * 8]);
            #pragma unroll
            for (int t = 0; t < 2; ++t)
                #pragma unroll
                for (int j = 0; j < 5; ++j)
                    accS[t][j] = __builtin_amdgcn_mfma_f32_16x16x32_bf16(
                        aq[t], bk[j], accS[t][j], 0, 0, 0);
        }

        // ---- softmax in registers (row's 80 cols live in 5 regs x 16 lanes) ----
        float pw[2][5][4];
        #pragma unroll
        for (int t = 0; t < 2; ++t) {
            #pragma unroll
            for (int r = 0; r < 4; ++r) {
                float v0 = accS[t][0][r] * 0.125f;
                float v1 = accS[t][1][r] * 0.125f;
                float v2 = accS[t][2][r] * 0.125f;
                float v3 = accS[t][3][r] * 0.125f;
                float v4 = v4ok ? accS[t][4][r] * 0.125f : -1e30f;
                float mx = fmaxf(fmaxf(fmaxf(v0, v1), fmaxf(v2, v3)), v4);
                mx = fmaxf(mx, __shfl_xor(mx, 1));
                mx = fmaxf(mx, __shfl_xor(mx, 2));
                mx = fmaxf(mx, __shfl_xor(mx, 4));
                mx = fmaxf(mx, __shfl_xor(mx, 8));
                float e0 = __expf(v0 - mx), e1 = __expf(v1 - mx);
                float e2 = __expf(v2 - mx), e3 = __expf(v3 - mx);
                float e4 = __expf(v4 - mx);
                float sum = e0 + e1 + e2 + e3 + e4;
                sum += __shfl_xor(sum, 1);
                sum += __shfl_xor(sum, 2);
                sum += __shfl_xor(sum, 4);
                sum += __shfl_xor(sum, 8);
                float inv = 1.f / sum;
                pw[t][0][r] = e0 * inv; pw[t][1][r] = e1 * inv;
                pw[t][2][r] = e2 * inv; pw[t][3][r] = e3 * inv;
                pw[t][4][r] = e4 * inv;
            }
        }
        __syncthreads();   // all QK^T reads of sQP done -> safe to overwrite with P

        // ---- write P (bf16) into sQP [row][c] stride 104; zero cols 80..95 ----
        #pragma unroll
        for (int t = 0; t < 2; ++t) {
            #pragma unroll
            for (int r = 0; r < 4; ++r) {
                int row = wm + t * 16 + quad * 4 + r;
                #pragma unroll
                for (int j = 0; j < 5; ++j)
                    sQP[row * 104 + j * 16 + l16] = f2bf(pw[t][j][r]);
                sQP[row * 104 + 80 + l16] = 0;
            }
        }
        __syncthreads();

        // ---- PV: out[128,64] = P[128,96] @ V[96,64] ----
        floatx4 accO[2][4] = {};
        #pragma unroll
        for (int kk = 0; kk < 3; ++kk) {
            bf16x8 aw[2], bv[4];
            #pragma unroll
            for (int t = 0; t < 2; ++t)
                aw[t] = *(const bf16x8*)(&sQP[(wm + t * 16 + l16) * 104 + kk * 32 + quad * 8]);
            #pragma unroll
            for (int j = 0; j < 4; ++j)
                bv[j] = *(const bf16x8*)(&vts[(j * 16 + l16) * 104 + kk * 32 + quad * 8]);
            #pragma unroll
            for (int t = 0; t < 2; ++t)
                #pragma unroll
                for (int j = 0; j < 4; ++j)
                    accO[t][j] = __builtin_amdgcn_mfma_f32_16x16x32_bf16(
                        aw[t], bv[j], accO[t][j], 0, 0, 0);
        }

        // ---- store out tile ----
        #pragma unroll
        for (int t = 0; t < 2; ++t)
            #pragma unroll
            for (int j = 0; j < 4; ++j)
                #pragma unroll
                for (int r = 0; r < 4; ++r) {
                    int row = wm + t * 16 + quad * 4 + r;
                    obase[(long)row * HS + j * 16 + l16] = f2bf(accO[t][j][r]);
                }
        __syncthreads();   // protect sQP before next iteration's q staging
    }
}

// ---------------------------------------------------------------------------
extern "C" void kernel_launch(void* const* d_in, const int* in_sizes, int n_in,
                              void* d_out, int out_size, void* d_ws, size_t ws_size,
                              hipStream_t stream) {
    const float* query   = (const float*)d_in[0];  // [16,4096,512] fp32
    const float* context = (const float*)d_in[1];  // [16,77,768]   fp32
    const float* Wq      = (const float*)d_in[2];  // [512,512]     fp32
    const float* Wk      = (const float*)d_in[3];  // [768,512]     fp32
    const float* Wv      = (const float*)d_in[4];  // [768,512]     fp32
    const float* Wo      = (const float*)d_in[5];  // [512,512]     fp32
    const float* bo      = (const float*)d_in[6];  // [512]         fp32
    float* out = (float*)d_out;                    // [16,4096,512] fp32

    // workspace layout (u16 elements) — total ~72.3 MB
    u16* q_ws  = (u16*)d_ws;            // 16*4096*512 (also attn out, in-place)
    u16* kv_ws = q_ws + 33554432;       // 1232*1024
    u16* WqT   = kv_ws + 1261568;       // 512*512
    u16* WkvT  = WqT + 262144;          // 1024*768
    u16* WoT   = WkvT + 786432;         // 512*512

    transpose_one<<<(512 * 512 + 255) / 256, 256, 0, stream>>>(Wq, WqT, 512, 512);
    transpose_kv<<<(1024 * 768 + 255) / 256, 256, 0, stream>>>(Wk, Wv, WkvT);
    transpose_one<<<(512 * 512 + 255) / 256, 256, 0, stream>>>(Wo, WoT, 512, 512);

    // q projection: [65536,512](fp32) x [512,512] -> bf16 ws
    // 512 M-tiles x 4 N-tiles = 2048 wgs (div by 8), ntl2 = 2
    gemm_bt<true, false><<<dim3(2048), 256, 0, stream>>>(
        (const void*)query, WqT, (void*)q_ws, nullptr, 65536, 512, 512, 2);
    // k,v projection fused: [1232,768](fp32) x [768,1024] -> bf16 ws
    // 10 M-tiles x 8 N-tiles = 80 wgs (div by 8), ntl2 = 3
    gemm_bt<true, false><<<dim3(80), 256, 0, stream>>>(
        (const void*)context, WkvT, (void*)kv_ws, nullptr, 1232, 768, 1024, 3);
    // attention, in-place on q_ws (bf16)
    attn_kernel<<<dim3(16, 8, 16), 256, 0, stream>>>(q_ws, kv_ws, q_ws);
    // output projection + fp32 bias: [65536,512](bf16) x [512,512] -> fp32 out
    gemm_bt<false, true><<<dim3(2048), 256, 0, stream>>>(
        (const void*)q_ws, WoT, (void*)out, bo, 65536, 512, 512, 2);
}

// Round 2
// 444.622 us; speedup vs baseline: 1.0832x; 1.0164x over previous
//
#include <hip/hip_runtime.h>

typedef unsigned short u16;
typedef unsigned int u32;
typedef __bf16 bf16_t;
typedef bf16_t bf16x8 __attribute__((ext_vector_type(8)));
typedef float floatx4 __attribute__((ext_vector_type(4)));

__device__ __forceinline__ float bf2f(u16 h) {
    union { unsigned u; float f; } v;
    v.u = ((unsigned)h) << 16;
    return v.f;
}

__device__ __forceinline__ u16 f2bf(float f) {
    union { float f; unsigned u; } v;
    v.f = f;
    unsigned r = v.u + 0x7fffu + ((v.u >> 16) & 1u);
    return (u16)(r >> 16);
}

// async global->LDS, 16B per lane. LDS dest = uniform base + lane*16 (HW rule).
typedef __attribute__((address_space(1))) const u32 gu32;
typedef __attribute__((address_space(3))) u32 lu32;
__device__ __forceinline__ void gload16(const void* g, void* l) {
    __builtin_amdgcn_global_load_lds((gu32*)g, (lu32*)l, 16, 0, 0);
}

// ---------------------------------------------------------------------------
// Weight transposes: fp32 in -> bf16 transposed out (tiny, L2-resident)
// ---------------------------------------------------------------------------
__global__ void transpose_one(const float* __restrict__ W, u16* __restrict__ Wt,
                              int K, int N) {
    int idx = blockIdx.x * 256 + threadIdx.x;
    if (idx >= K * N) return;
    int nrow = idx / K;
    int k = idx - nrow * K;
    Wt[idx] = f2bf(W[k * N + nrow]);   // Wt[n][k] = W[k][n]
}

// WkvT [1024][768]: rows 0..511 = Wk^T, rows 512..1023 = Wv^T
__global__ void transpose_kv(const float* __restrict__ Wk, const float* __restrict__ Wv,
                             u16* __restrict__ Wt) {
    int idx = blockIdx.x * 256 + threadIdx.x;
    if (idx >= 1024 * 768) return;
    int nrow = idx / 768;
    int k = idx - nrow * 768;
    Wt[idx] = f2bf((nrow < 512) ? Wk[k * 512 + nrow] : Wv[k * 512 + (nrow - 512)]);
}

// V^T for attention: vt[((n*8+h)*64+s)*96 + c] = v[n][c][h][s], zero c>=77.
// Tiny (1.5 MB), kv_ws is L2-resident. Writes coalesced, reads scattered.
__global__ void transpose_v(const u16* __restrict__ kv, u16* __restrict__ vt) {
    int idx = blockIdx.x * 256 + threadIdx.x;
    if (idx >= 16 * 8 * 64 * 96) return;
    int c  = idx % 96;
    int t1 = idx / 96;
    int s  = t1 & 63;
    int t2 = t1 >> 6;
    int h  = t2 & 7;
    int n  = t2 >> 3;
    u16 val = 0;
    if (c < 77) val = kv[((long)(n * 77 + c)) * 1024 + 512 + h * 64 + s];
    vt[idx] = val;
}

// ---------------------------------------------------------------------------
// GEMM: C[M,N] = A[M,K] * Bt[N,K]^T (+bias), bf16 MFMA, fp32 accum.
// 2-phase double-buffered pipeline (T3 minimum): STAGE(next) issued BEFORE
// compute(cur); single __syncthreads (vmcnt(0)+barrier) per K-step, so the
// next tile's global_load_lds latency hides under the current tile's MFMA.
// fp32-A tiles use XOR chunk swizzle (source-side + read-side, linear LDS
// dest per rule #21) to kill the 16-way bank conflict of 128B-stride rows.
// Requires: gridDim.x % 8 == 0, K % 32 == 0, N % 128 == 0.
// ---------------------------------------------------------------------------
#define TM 128
#define TN 128
#define TK 32

template <bool A_F32, bool OUT_F32>
__global__ __launch_bounds__(256) void gemm_bt(
    const void* __restrict__ A_, const u16* __restrict__ Bt,
    void* __restrict__ C_, const float* __restrict__ bias,
    int M, int K, int N, int ntl2)   // ntl2 = log2(# N tiles)
{
    constexpr int AB = A_F32 ? TM * TK * 4 : TM * TK * 2;   // A tile bytes
    constexpr int BB = TN * TK * 2;                          // B tile bytes
    __shared__ __align__(16) char smem[2 * (AB + BB)];

    const int tid  = threadIdx.x;
    const int lane = tid & 63;
    const int wave = tid >> 6;
    const int quad = lane >> 4;
    const int l16  = lane & 15;
    const int wm   = (wave & 1) * 64;
    const int wn   = (wave >> 1) * 64;

    // XCD-aware bijective swizzle (nwg % 8 == 0), N-tile fastest within XCD.
    const int nwg = gridDim.x;
    const int wg  = blockIdx.x;
    const int t   = (wg & 7) * (nwg >> 3) + (wg >> 3);
    const long bm = (long)(t >> ntl2) * TM;
    const long bn = (long)(t & ((1 << ntl2) - 1)) * TN;

    const float* Af = (const float*)A_;
    const u16*   Ab = (const u16*)A_;

    floatx4 acc[4][4] = {};

    auto stage = [&](int b, int k0) {
        char* Abase = smem + b * (AB + BB);
        u16*  Bb    = (u16*)(Abase + AB);
        // ---- B: 128x32 bf16 = 512 x 16B chunks, linear LDS ----
        #pragma unroll
        for (int p = 0; p < 2; ++p) {
            int ch  = p * 256 + tid;
            int row = ch >> 2;
            int pc  = ch & 3;
            gload16(Bt + (bn + row) * K + k0 + pc * 8,
                    Bb + (p * 256 + wave * 64) * 8);
        }
        if (A_F32) {
            // ---- A fp32: 128x32 = 1024 chunks; source-side XOR swizzle ----
            #pragma unroll
            for (int p = 0; p < 4; ++p) {
                int ch  = p * 256 + tid;
                int row = ch >> 3;
                int pcs = (ch & 7) ^ (row & 7);   // swizzled source chunk
                long gr = bm + row;
                if (gr < M)
                    gload16(Af + gr * K + k0 + pcs * 4,
                            (float*)Abase + (p * 256 + wave * 64) * 4);
            }
        } else {
            // ---- A bf16: 128x32 = 512 chunks, linear (64B rows: 2-way = free)
            #pragma unroll
            for (int p = 0; p < 2; ++p) {
                int ch  = p * 256 + tid;
                int row = ch >> 2;
                int pc  = ch & 3;
                long gr = bm + row;
                if (gr < M)
                    gload16(Ab + gr * K + k0 + pc * 8,
                            (u16*)Abase + (p * 256 + wave * 64) * 8);
            }
        }
    };

    const int nk = K / TK;
    stage(0, 0);
    __syncthreads();   // vmcnt(0) drain: tile 0 resident

    for (int tt = 0; tt < nk; ++tt) {
        const int cb = tt & 1;
        if (tt + 1 < nk) stage(cb ^ 1, (tt + 1) * TK);   // prefetch next tile

        const char* Abase = smem + cb * (AB + BB);
        const u16*  Bb    = (const u16*)(Abase + AB);

        bf16x8 af[4], bfr[4];
        #pragma unroll
        for (int i = 0; i < 4; ++i) {
            int row = wm + i * 16 + l16;
            if (A_F32) {
                const char* arow = Abase + (size_t)row * 128;
                int x = row & 7;
                float4 f0 = *(const float4*)(arow + (((quad * 2)     ^ x) * 16));
                float4 f1 = *(const float4*)(arow + (((quad * 2 + 1) ^ x) * 16));
                union { bf16_t h[8]; bf16x8 v; } pk;
                pk.h[0] = (bf16_t)f0.x; pk.h[1] = (bf16_t)f0.y;
                pk.h[2] = (bf16_t)f0.z; pk.h[3] = (bf16_t)f0.w;
                pk.h[4] = (bf16_t)f1.x; pk.h[5] = (bf16_t)f1.y;
                pk.h[6] = (bf16_t)f1.z; pk.h[7] = (bf16_t)f1.w;
                af[i] = pk.v;
            } else {
                af[i] = *(const bf16x8*)((const u16*)Abase + row * 32 + quad * 8);
            }
        }
        #pragma unroll
        for (int j = 0; j < 4; ++j)
            bfr[j] = *(const bf16x8*)(Bb + (wn + j * 16 + l16) * 32 + quad * 8);
        #pragma unroll
        for (int i = 0; i < 4; ++i)
            #pragma unroll
            for (int j = 0; j < 4; ++j)
                acc[i][j] = __builtin_amdgcn_mfma_f32_16x16x32_bf16(
                    af[i], bfr[j], acc[i][j], 0, 0, 0);

        __syncthreads();   // drains prefetch vmcnt + protects cur buffer
    }

    #pragma unroll
    for (int i = 0; i < 4; ++i) {
        #pragma unroll
        for (int r = 0; r < 4; ++r) {
            long row = bm + wm + i * 16 + quad * 4 + r;
            if (row >= M) continue;
            #pragma unroll
            for (int j = 0; j < 4; ++j) {
                long col = bn + wn + j * 16 + l16;
                float val = acc[i][j][r];
                if (bias) val += bias[col];
                if (OUT_F32) ((float*)C_)[row * N + col] = val;
                else         ((u16*)C_)[row * N + col] = f2bf(val);
            }
        }
    }
}

// ---------------------------------------------------------------------------
// Fused attention v3. Grid (qc=16, h=8, n=16); block = 256 q-rows of one
// (n,h), processed as 2 tiles of 128. k staged from kv_ws; V^T staged
// directly from pre-transposed vt_ws (removes LDS->LDS transpose + barrier).
// Softmax entirely in registers via __shfl_xor; q-tile and P share one LDS
// buffer. In-place safe (block reads exactly the q slice it writes).
// ---------------------------------------------------------------------------
__global__ __launch_bounds__(256) void attn_kernel(
    const u16* __restrict__ qb,   // [N, 4096, 512] bf16
    const u16* __restrict__ kvb,  // [N*77, 1024] bf16 (cols 0..511 k)
    const u16* __restrict__ vt,   // [(n*8+h)*64+s][96] bf16, zero c>=77
    u16* __restrict__ ob)         // [N, 4096, 512] bf16
{
    const int QL = 4096, HS = 512;
    const int q0 = blockIdx.x * 256;
    const int h  = blockIdx.y;
    const int n  = blockIdx.z;

    __shared__ u16 sQP[128 * 104];  // q tile (stride 72) / P (stride 104): 26.6 KB
    __shared__ u16 ks [80 * 72];    // k [c][s], c zero-padded to 80: 11.5 KB
    __shared__ u16 vts[64 * 104];   // V^T [s][c]: 13.3 KB

    const int tid  = threadIdx.x;
    const int lane = tid & 63;
    const int wave = tid >> 6;
    const int quad = lane >> 4;
    const int l16  = lane & 15;
    const int wm   = wave * 32;     // wave's q-row offset within 128-tile

    // ---- stage k rows (coalesced, zero-pad c>=77) ----
    const u16* kbase = kvb + (long)n * 77 * 1024 + h * 64;
    for (int v = tid; v < 640; v += 256) {
        int c = v >> 3, g = (v & 7) * 8;
        uint4 val = make_uint4(0, 0, 0, 0);
        if (c < 77) val = *(const uint4*)(kbase + (long)c * 1024 + g);
        *(uint4*)(&ks[c * 72 + g]) = val;
    }
    // ---- stage V^T rows from vt_ws (linear global, stride-104 LDS) ----
    const u16* vtbase = vt + (long)((n * 8 + h) * 64) * 96;
    for (int v = tid; v < 768; v += 256) {           // 64 rows x 12 uint4
        int r = v / 12, c8 = v - r * 12;
        *(uint4*)(&vts[r * 104 + c8 * 8]) = *(const uint4*)(vtbase + v * 8);
    }
    __syncthreads();

    const bool v4ok = (l16 < 13);   // j=4 -> c = 64+l16, valid iff c<77

    for (int it = 0; it < 2; ++it) {
        const long qrow0 = (long)q0 + it * 128;
        const u16* qbase = qb + ((long)n * QL + qrow0) * HS + h * 64;
        u16*       obase = ob + ((long)n * QL + qrow0) * HS + h * 64;

        // ---- stage q tile 128x64 (stride 72) ----
        #pragma unroll
        for (int p = 0; p < 4; ++p) {
            int v = tid + p * 256;
            int r = v >> 3, g = (v & 7) * 8;
            *(uint4*)(&sQP[r * 72 + g]) = *(const uint4*)(qbase + (long)r * HS + g);
        }
        __syncthreads();

        // ---- QK^T: wave covers rows wm..wm+31 (2 row-tiles x 5 col-tiles) ----
        floatx4 accS[2][5] = {};
        #pragma unroll
        for (int kk = 0; kk < 2; ++kk) {
            bf16x8 aq[2], bk[5];
            #pragma unroll
            for (int t = 0; t < 2; ++t)
                aq[t] = *(const bf16x8*)(&sQP[(wm + t * 16 + l16) * 72 + kk * 32 + quad * 8]);
            #pragma unroll
            for (int j = 0; j < 5; ++j)
                bk[j] = *(const bf16x8*)(&ks[(j * 16 + l16) * 72 + kk * 32 + quad * 8]);
            #pragma unroll
            for (int t = 0; t < 2; ++t)
                #pragma unroll
                for (int j = 0; j < 5; ++j)
                    accS[t][j] = __builtin_amdgcn_mfma_f32_16x16x32_bf16(
                        aq[t], bk[j], accS[t][j], 0, 0, 0);
        }

        // ---- softmax in registers (row's 80 cols live in 5 regs x 16 lanes) ----
        float pw[2][5][4];
        #pragma unroll
        for (int t = 0; t < 2; ++t) {
            #pragma unroll
            for (int r = 0; r < 4; ++r) {
                float v0 = accS[t][0][r] * 0.125f;
                float v1 = accS[t][1][r] * 0.125f;
                float v2 = accS[t][2][r] * 0.125f;
                float v3 = accS[t][3][r] * 0.125f;
                float v4 = v4ok ? accS[t][4][r] * 0.125f : -1e30f;
                float mx = fmaxf(fmaxf(fmaxf(v0, v1), fmaxf(v2, v3)), v4);
                mx = fmaxf(mx, __shfl_xor(mx, 1));
                mx = fmaxf(mx, __shfl_xor(mx, 2));
                mx = fmaxf(mx, __shfl_xor(mx, 4));
                mx = fmaxf(mx, __shfl_xor(mx, 8));
                float e0 = __expf(v0 - mx), e1 = __expf(v1 - mx);
                float e2 = __expf(v2 - mx), e3 = __expf(v3 - mx);
                float e4 = __expf(v4 - mx);
                float sum = e0 + e1 + e2 + e3 + e4;
                sum += __shfl_xor(sum, 1);
                sum += __shfl_xor(sum, 2);
                sum += __shfl_xor(sum, 4);
                sum += __shfl_xor(sum, 8);
                float inv = 1.f / sum;
                pw[t][0][r] = e0 * inv; pw[t][1][r] = e1 * inv;
                pw[t][2][r] = e2 * inv; pw[t][3][r] = e3 * inv;
                pw[t][4][r] = e4 * inv;
            }
        }
        __syncthreads();   // all QK^T reads of sQP done -> safe to overwrite with P

        // ---- write P (bf16) into sQP [row][c] stride 104; zero cols 80..95 ----
        #pragma unroll
        for (int t = 0; t < 2; ++t) {
            #pragma unroll
            for (int r = 0; r < 4; ++r) {
                int row = wm + t * 16 + quad * 4 + r;
                #pragma unroll
                for (int j = 0; j < 5; ++j)
                    sQP[row * 104 + j * 16 + l16] = f2bf(pw[t][j][r]);
                sQP[row * 104 + 80 + l16] = 0;
            }
        }
        __syncthreads();

        // ---- PV: out[128,64] = P[128,96] @ V[96,64] ----
        floatx4 accO[2][4] = {};
        #pragma unroll
        for (int kk = 0; kk < 3; ++kk) {
            bf16x8 aw[2], bv[4];
            #pragma unroll
            for (int t = 0; t < 2; ++t)
                aw[t] = *(const bf16x8*)(&sQP[(wm + t * 16 + l16) * 104 + kk * 32 + quad * 8]);
            #pragma unroll
            for (int j = 0; j < 4; ++j)
                bv[j] = *(const bf16x8*)(&vts[(j * 16 + l16) * 104 + kk * 32 + quad * 8]);
            #pragma unroll
            for (int t = 0; t < 2; ++t)
                #pragma unroll
                for (int j = 0; j < 4; ++j)
                    accO[t][j] = __builtin_amdgcn_mfma_f32_16x16x32_bf16(
                        aw[t], bv[j], accO[t][j], 0, 0, 0);
        }

        // ---- store out tile ----
        #pragma unroll
        for (int t = 0; t < 2; ++t)
            #pragma unroll
            for (int j = 0; j < 4; ++j)
                #pragma unroll
                for (int r = 0; r < 4; ++r) {
                    int row = wm + t * 16 + quad * 4 + r;
                    obase[(long)row * HS + j * 16 + l16] = f2bf(accO[t][j][r]);
                }
        __syncthreads();   // protect sQP before next iteration's q staging
    }
}

// ---------------------------------------------------------------------------
extern "C" void kernel_launch(void* const* d_in, const int* in_sizes, int n_in,
                              void* d_out, int out_size, void* d_ws, size_t ws_size,
                              hipStream_t stream) {
    const float* query   = (const float*)d_in[0];  // [16,4096,512] fp32
    const float* context = (const float*)d_in[1];  // [16,77,768]   fp32
    const float* Wq      = (const float*)d_in[2];  // [512,512]     fp32
    const float* Wk      = (const float*)d_in[3];  // [768,512]     fp32
    const float* Wv      = (const float*)d_in[4];  // [768,512]     fp32
    const float* Wo      = (const float*)d_in[5];  // [512,512]     fp32
    const float* bo      = (const float*)d_in[6];  // [512]         fp32
    float* out = (float*)d_out;                    // [16,4096,512] fp32

    // workspace layout (u16 elements) — total ~72.3 MB
    u16* q_ws  = (u16*)d_ws;            // 16*4096*512 (also attn out, in-place)
    u16* kv_ws = q_ws + 33554432;       // 1232*1024
    u16* WqT   = kv_ws + 1261568;       // 512*512
    u16* WkvT  = WqT + 262144;          // 1024*768
    u16* WoT   = WkvT + 786432;         // 512*512
    // vt_ws reuses WkvT's region: WkvT is dead after the kv-proj GEMM, and
    // transpose_v runs after it on the same stream. Same size (786432 u16).
    u16* vt_ws = WkvT;

    transpose_one<<<(512 * 512 + 255) / 256, 256, 0, stream>>>(Wq, WqT, 512, 512);
    transpose_kv<<<(1024 * 768 + 255) / 256, 256, 0, stream>>>(Wk, Wv, WkvT);
    transpose_one<<<(512 * 512 + 255) / 256, 256, 0, stream>>>(Wo, WoT, 512, 512);

    // q projection: [65536,512](fp32) x [512,512] -> bf16 ws
    // 512 M-tiles x 4 N-tiles = 2048 wgs (div by 8), ntl2 = 2
    gemm_bt<true, false><<<dim3(2048), 256, 0, stream>>>(
        (const void*)query, WqT, (void*)q_ws, nullptr, 65536, 512, 512, 2);
    // k,v projection fused: [1232,768](fp32) x [768,1024] -> bf16 ws
    // 10 M-tiles x 8 N-tiles = 80 wgs (div by 8), ntl2 = 3
    gemm_bt<true, false><<<dim3(80), 256, 0, stream>>>(
        (const void*)context, WkvT, (void*)kv_ws, nullptr, 1232, 768, 1024, 3);
    // V^T scatter (overwrites WkvT region, which is now dead)
    transpose_v<<<(16 * 8 * 64 * 96 + 255) / 256, 256, 0, stream>>>(kv_ws, vt_ws);
    // attention, in-place on q_ws (bf16)
    attn_kernel<<<dim3(16, 8, 16), 256, 0, stream>>>(q_ws, kv_ws, vt_ws, q_ws);
    // output projection + fp32 bias: [65536,512](bf16) x [512,512] -> fp32 out
    gemm_bt<false, true><<<dim3(2048), 256, 0, stream>>>(
        (const void*)q_ws, WoT, (void*)out, bo, 65536, 512, 512, 2);
}

// Round 3
// 424.710 us; speedup vs baseline: 1.1340x; 1.0469x over previous
//
#include <hip/hip_runtime.h>

typedef unsigned short u16;
typedef unsigned int u32;
typedef __bf16 bf16_t;
typedef bf16_t bf16x8 __attribute__((ext_vector_type(8)));
typedef float floatx4 __attribute__((ext_vector_type(4)));

__device__ __forceinline__ float bf2f(u16 h) {
    union { unsigned u; float f; } v;
    v.u = ((unsigned)h) << 16;
    return v.f;
}

__device__ __forceinline__ u16 f2bf(float f) {
    union { float f; unsigned u; } v;
    v.f = f;
    unsigned r = v.u + 0x7fffu + ((v.u >> 16) & 1u);
    return (u16)(r >> 16);
}

// async global->LDS, 16B per lane. LDS dest = uniform base + lane*16 (HW rule).
typedef __attribute__((address_space(1))) const u32 gu32;
typedef __attribute__((address_space(3))) u32 lu32;
__device__ __forceinline__ void gload16(const void* g, void* l) {
    __builtin_amdgcn_global_load_lds((gu32*)g, (lu32*)l, 16, 0, 0);
}

// ---------------------------------------------------------------------------
// Weight transposes: fp32 in -> bf16 transposed out (tiny, L2-resident)
// ---------------------------------------------------------------------------
__global__ void transpose_one(const float* __restrict__ W, u16* __restrict__ Wt,
                              int K, int N) {
    int idx = blockIdx.x * 256 + threadIdx.x;
    if (idx >= K * N) return;
    int nrow = idx / K;
    int k = idx - nrow * K;
    Wt[idx] = f2bf(W[k * N + nrow]);   // Wt[n][k] = W[k][n]
}

// WkvT [1024][768]: rows 0..511 = Wk^T, rows 512..1023 = Wv^T
__global__ void transpose_kv(const float* __restrict__ Wk, const float* __restrict__ Wv,
                             u16* __restrict__ Wt) {
    int idx = blockIdx.x * 256 + threadIdx.x;
    if (idx >= 1024 * 768) return;
    int nrow = idx / 768;
    int k = idx - nrow * 768;
    Wt[idx] = f2bf((nrow < 512) ? Wk[k * 512 + nrow] : Wv[k * 512 + (nrow - 512)]);
}

// V^T for attention: vt[((n*8+h)*64+s)*96 + c] = v[n][c][h][s], zero c>=77.
__global__ void transpose_v(const u16* __restrict__ kv, u16* __restrict__ vt) {
    int idx = blockIdx.x * 256 + threadIdx.x;
    if (idx >= 16 * 8 * 64 * 96) return;
    int c  = idx % 96;
    int t1 = idx / 96;
    int s  = t1 & 63;
    int t2 = t1 >> 6;
    int h  = t2 & 7;
    int n  = t2 >> 3;
    u16 val = 0;
    if (c < 77) val = kv[((long)(n * 77 + c)) * 1024 + 512 + h * 64 + s];
    vt[idx] = val;
}

// ---------------------------------------------------------------------------
// GEMM: C[M,N] = A[M,K] * Bt[N,K]^T (+bias), bf16 MFMA, fp32 accum.
// Wide-block variant: TM=128 x TN=256, 512 threads (8 waves, 2M x 4N grid,
// acc[4][4] per wave). 2x FLOP per K-step per barrier vs 128x128; launch
// bounds force <=128 VGPR -> 2 blocks/CU = 4 waves/SIMD for latency cover.
// Double-buffered LDS, global_load_lds staging, XCD-aware swizzle with
// N-tiles innermost (A-panel read 2x, second hit in same-XCD L2).
// Requires: gridDim.x % 8 == 0, K % 32 == 0, N % 256 == 0.
// ---------------------------------------------------------------------------
#define TM 128
#define TN 256
#define TK 32

template <bool A_F32, bool OUT_F32>
__global__ __launch_bounds__(512, 4) void gemm_bt(
    const void* __restrict__ A_, const u16* __restrict__ Bt,
    void* __restrict__ C_, const float* __restrict__ bias,
    int M, int K, int N, int ntl2)   // ntl2 = log2(# N tiles)
{
    constexpr int AB = A_F32 ? TM * TK * 4 : TM * TK * 2;   // A tile bytes
    constexpr int BB = TN * TK * 2;                          // B tile bytes
    __shared__ __align__(16) char smem[2 * (AB + BB)];

    const int tid  = threadIdx.x;
    const int lane = tid & 63;
    const int wave = tid >> 6;          // 0..7
    const int quad = lane >> 4;
    const int l16  = lane & 15;
    const int wm   = (wave & 1) * 64;   // 2 M-waves
    const int wn   = (wave >> 1) * 64;  // 4 N-waves -> covers 256

    // XCD-aware bijective swizzle (nwg % 8 == 0), N-tile fastest within XCD.
    const int nwg = gridDim.x;
    const int wg  = blockIdx.x;
    const int t   = (wg & 7) * (nwg >> 3) + (wg >> 3);
    const long bm = (long)(t >> ntl2) * TM;
    const long bn = (long)(t & ((1 << ntl2) - 1)) * TN;

    const float* Af = (const float*)A_;
    const u16*   Ab = (const u16*)A_;

    floatx4 acc[4][4] = {};

    auto stage = [&](int b, int k0) {
        char* Abase = smem + b * (AB + BB);
        u16*  Bb    = (u16*)(Abase + AB);
        // ---- B: 256x32 bf16 = 1024 x 16B chunks, 2/thread, linear LDS ----
        #pragma unroll
        for (int p = 0; p < 2; ++p) {
            int ch  = p * 512 + tid;
            int row = ch >> 2;
            int pc  = ch & 3;
            gload16(Bt + (bn + row) * K + k0 + pc * 8,
                    Bb + (p * 512 + wave * 64) * 8);
        }
        if (A_F32) {
            // ---- A fp32: 128x32 = 1024 chunks, 2/thread; XOR src swizzle ----
            #pragma unroll
            for (int p = 0; p < 2; ++p) {
                int ch  = p * 512 + tid;
                int row = ch >> 3;
                int pcs = (ch & 7) ^ (row & 7);
                long gr = bm + row;
                if (gr < M)
                    gload16(Af + gr * K + k0 + pcs * 4,
                            (float*)Abase + (p * 512 + wave * 64) * 4);
            }
        } else {
            // ---- A bf16: 128x32 = 512 chunks, 1/thread, linear ----
            int row = tid >> 2;
            int pc  = tid & 3;
            long gr = bm + row;
            if (gr < M)
                gload16(Ab + gr * K + k0 + pc * 8,
                        (u16*)Abase + (wave * 64) * 8);
        }
    };

    const int nk = K / TK;
    stage(0, 0);
    __syncthreads();   // vmcnt(0) drain: tile 0 resident

    for (int tt = 0; tt < nk; ++tt) {
        const int cb = tt & 1;
        if (tt + 1 < nk) stage(cb ^ 1, (tt + 1) * TK);   // prefetch next tile

        const char* Abase = smem + cb * (AB + BB);
        const u16*  Bb    = (const u16*)(Abase + AB);

        bf16x8 af[4], bfr[4];
        #pragma unroll
        for (int i = 0; i < 4; ++i) {
            int row = wm + i * 16 + l16;
            if (A_F32) {
                const char* arow = Abase + (size_t)row * 128;
                int x = row & 7;
                float4 f0 = *(const float4*)(arow + (((quad * 2)     ^ x) * 16));
                float4 f1 = *(const float4*)(arow + (((quad * 2 + 1) ^ x) * 16));
                union { bf16_t h[8]; bf16x8 v; } pk;
                pk.h[0] = (bf16_t)f0.x; pk.h[1] = (bf16_t)f0.y;
                pk.h[2] = (bf16_t)f0.z; pk.h[3] = (bf16_t)f0.w;
                pk.h[4] = (bf16_t)f1.x; pk.h[5] = (bf16_t)f1.y;
                pk.h[6] = (bf16_t)f1.z; pk.h[7] = (bf16_t)f1.w;
                af[i] = pk.v;
            } else {
                af[i] = *(const bf16x8*)((const u16*)Abase + row * 32 + quad * 8);
            }
        }
        #pragma unroll
        for (int j = 0; j < 4; ++j)
            bfr[j] = *(const bf16x8*)(Bb + (wn + j * 16 + l16) * 32 + quad * 8);
        #pragma unroll
        for (int i = 0; i < 4; ++i)
            #pragma unroll
            for (int j = 0; j < 4; ++j)
                acc[i][j] = __builtin_amdgcn_mfma_f32_16x16x32_bf16(
                    af[i], bfr[j], acc[i][j], 0, 0, 0);

        __syncthreads();   // drains prefetch vmcnt + protects cur buffer
    }

    #pragma unroll
    for (int i = 0; i < 4; ++i) {
        #pragma unroll
        for (int r = 0; r < 4; ++r) {
            long row = bm + wm + i * 16 + quad * 4 + r;
            if (row >= M) continue;
            #pragma unroll
            for (int j = 0; j < 4; ++j) {
                long col = bn + wn + j * 16 + l16;
                float val = acc[i][j][r];
                if (bias) val += bias[col];
                if (OUT_F32) ((float*)C_)[row * N + col] = val;
                else         ((u16*)C_)[row * N + col] = f2bf(val);
            }
        }
    }
}

// ---------------------------------------------------------------------------
// Fused attention v3 (unchanged this round). Grid (qc=16, h=8, n=16).
// ---------------------------------------------------------------------------
__global__ __launch_bounds__(256) void attn_kernel(
    const u16* __restrict__ qb,   // [N, 4096, 512] bf16
    const u16* __restrict__ kvb,  // [N*77, 1024] bf16 (cols 0..511 k)
    const u16* __restrict__ vt,   // [(n*8+h)*64+s][96] bf16, zero c>=77
    u16* __restrict__ ob)         // [N, 4096, 512] bf16
{
    const int QL = 4096, HS = 512;
    const int q0 = blockIdx.x * 256;
    const int h  = blockIdx.y;
    const int n  = blockIdx.z;

    __shared__ u16 sQP[128 * 104];  // q tile (stride 72) / P (stride 104)
    __shared__ u16 ks [80 * 72];    // k [c][s], c zero-padded to 80
    __shared__ u16 vts[64 * 104];   // V^T [s][c]

    const int tid  = threadIdx.x;
    const int lane = tid & 63;
    const int wave = tid >> 6;
    const int quad = lane >> 4;
    const int l16  = lane & 15;
    const int wm   = wave * 32;

    const u16* kbase = kvb + (long)n * 77 * 1024 + h * 64;
    for (int v = tid; v < 640; v += 256) {
        int c = v >> 3, g = (v & 7) * 8;
        uint4 val = make_uint4(0, 0, 0, 0);
        if (c < 77) val = *(const uint4*)(kbase + (long)c * 1024 + g);
        *(uint4*)(&ks[c * 72 + g]) = val;
    }
    const u16* vtbase = vt + (long)((n * 8 + h) * 64) * 96;
    for (int v = tid; v < 768; v += 256) {           // 64 rows x 12 uint4
        int r = v / 12, c8 = v - r * 12;
        *(uint4*)(&vts[r * 104 + c8 * 8]) = *(const uint4*)(vtbase + v * 8);
    }
    __syncthreads();

    const bool v4ok = (l16 < 13);

    for (int it = 0; it < 2; ++it) {
        const long qrow0 = (long)q0 + it * 128;
        const u16* qbase = qb + ((long)n * QL + qrow0) * HS + h * 64;
        u16*       obase = ob + ((long)n * QL + qrow0) * HS + h * 64;

        #pragma unroll
        for (int p = 0; p < 4; ++p) {
            int v = tid + p * 256;
            int r = v >> 3, g = (v & 7) * 8;
            *(uint4*)(&sQP[r * 72 + g]) = *(const uint4*)(qbase + (long)r * HS + g);
        }
        __syncthreads();

        floatx4 accS[2][5] = {};
        #pragma unroll
        for (int kk = 0; kk < 2; ++kk) {
            bf16x8 aq[2], bk[5];
            #pragma unroll
            for (int t = 0; t < 2; ++t)
                aq[t] = *(const bf16x8*)(&sQP[(wm + t * 16 + l16) * 72 + kk * 32 + quad * 8]);
            #pragma unroll
            for (int j = 0; j < 5; ++j)
                bk[j] = *(const bf16x8*)(&ks[(j * 16 + l16) * 72 + kk * 32 + quad * 8]);
            #pragma unroll
            for (int t = 0; t < 2; ++t)
                #pragma unroll
                for (int j = 0; j < 5; ++j)
                    accS[t][j] = __builtin_amdgcn_mfma_f32_16x16x32_bf16(
                        aq[t], bk[j], accS[t][j], 0, 0, 0);
        }

        float pw[2][5][4];
        #pragma unroll
        for (int t = 0; t < 2; ++t) {
            #pragma unroll
            for (int r = 0; r < 4; ++r) {
                float v0 = accS[t][0][r] * 0.125f;
                float v1 = accS[t][1][r] * 0.125f;
                float v2 = accS[t][2][r] * 0.125f;
                float v3 = accS[t][3][r] * 0.125f;
                float v4 = v4ok ? accS[t][4][r] * 0.125f : -1e30f;
                float mx = fmaxf(fmaxf(fmaxf(v0, v1), fmaxf(v2, v3)), v4);
                mx = fmaxf(mx, __shfl_xor(mx, 1));
                mx = fmaxf(mx, __shfl_xor(mx, 2));
                mx = fmaxf(mx, __shfl_xor(mx, 4));
                mx = fmaxf(mx, __shfl_xor(mx, 8));
                float e0 = __expf(v0 - mx), e1 = __expf(v1 - mx);
                float e2 = __expf(v2 - mx), e3 = __expf(v3 - mx);
                float e4 = __expf(v4 - mx);
                float sum = e0 + e1 + e2 + e3 + e4;
                sum += __shfl_xor(sum, 1);
                sum += __shfl_xor(sum, 2);
                sum += __shfl_xor(sum, 4);
                sum += __shfl_xor(sum, 8);
                float inv = 1.f / sum;
                pw[t][0][r] = e0 * inv; pw[t][1][r] = e1 * inv;
                pw[t][2][r] = e2 * inv; pw[t][3][r] = e3 * inv;
                pw[t][4][r] = e4 * inv;
            }
        }
        __syncthreads();

        #pragma unroll
        for (int t = 0; t < 2; ++t) {
            #pragma unroll
            for (int r = 0; r < 4; ++r) {
                int row = wm + t * 16 + quad * 4 + r;
                #pragma unroll
                for (int j = 0; j < 5; ++j)
                    sQP[row * 104 + j * 16 + l16] = f2bf(pw[t][j][r]);
                sQP[row * 104 + 80 + l16] = 0;
            }
        }
        __syncthreads();

        floatx4 accO[2][4] = {};
        #pragma unroll
        for (int kk = 0; kk < 3; ++kk) {
            bf16x8 aw[2], bv[4];
            #pragma unroll
            for (int t = 0; t < 2; ++t)
                aw[t] = *(const bf16x8*)(&sQP[(wm + t * 16 + l16) * 104 + kk * 32 + quad * 8]);
            #pragma unroll
            for (int j = 0; j < 4; ++j)
                bv[j] = *(const bf16x8*)(&vts[(j * 16 + l16) * 104 + kk * 32 + quad * 8]);
            #pragma unroll
            for (int t = 0; t < 2; ++t)
                #pragma unroll
                for (int j = 0; j < 4; ++j)
                    accO[t][j] = __builtin_amdgcn_mfma_f32_16x16x32_bf16(
                        aw[t], bv[j], accO[t][j], 0, 0, 0);
        }

        #pragma unroll
        for (int t = 0; t < 2; ++t)
            #pragma unroll
            for (int j = 0; j < 4; ++j)
                #pragma unroll
                for (int r = 0; r < 4; ++r) {
                    int row = wm + t * 16 + quad * 4 + r;
                    obase[(long)row * HS + j * 16 + l16] = f2bf(accO[t][j][r]);
                }
        __syncthreads();
    }
}

// ---------------------------------------------------------------------------
extern "C" void kernel_launch(void* const* d_in, const int* in_sizes, int n_in,
                              void* d_out, int out_size, void* d_ws, size_t ws_size,
                              hipStream_t stream) {
    const float* query   = (const float*)d_in[0];  // [16,4096,512] fp32
    const float* context = (const float*)d_in[1];  // [16,77,768]   fp32
    const float* Wq      = (const float*)d_in[2];  // [512,512]     fp32
    const float* Wk      = (const float*)d_in[3];  // [768,512]     fp32
    const float* Wv      = (const float*)d_in[4];  // [768,512]     fp32
    const float* Wo      = (const float*)d_in[5];  // [512,512]     fp32
    const float* bo      = (const float*)d_in[6];  // [512]         fp32
    float* out = (float*)d_out;                    // [16,4096,512] fp32

    // workspace layout (u16 elements)
    u16* q_ws  = (u16*)d_ws;            // 16*4096*512 (also attn out, in-place)
    u16* kv_ws = q_ws + 33554432;       // 1232*1024
    u16* WqT   = kv_ws + 1261568;       // 512*512
    u16* WkvT  = WqT + 262144;          // 1024*768
    u16* WoT   = WkvT + 786432;         // 512*512
    u16* vt_ws = WkvT;                  // reuse (WkvT dead after kv-proj)

    transpose_one<<<(512 * 512 + 255) / 256, 256, 0, stream>>>(Wq, WqT, 512, 512);
    transpose_kv<<<(1024 * 768 + 255) / 256, 256, 0, stream>>>(Wk, Wv, WkvT);
    transpose_one<<<(512 * 512 + 255) / 256, 256, 0, stream>>>(Wo, WoT, 512, 512);

    // q projection: [65536,512](fp32) x [512,512] -> bf16 ws
    // 512 M-tiles x 2 N-tiles = 1024 wgs (div 8), ntl2 = 1
    gemm_bt<true, false><<<dim3(1024), 512, 0, stream>>>(
        (const void*)query, WqT, (void*)q_ws, nullptr, 65536, 512, 512, 1);
    // k,v projection fused: [1232,768](fp32) x [768,1024] -> bf16 ws
    // 10 M-tiles x 4 N-tiles = 40 wgs (div 8), ntl2 = 2
    gemm_bt<true, false><<<dim3(40), 512, 0, stream>>>(
        (const void*)context, WkvT, (void*)kv_ws, nullptr, 1232, 768, 1024, 2);
    // V^T scatter (overwrites WkvT region, which is now dead)
    transpose_v<<<(16 * 8 * 64 * 96 + 255) / 256, 256, 0, stream>>>(kv_ws, vt_ws);
    // attention, in-place on q_ws (bf16)
    attn_kernel<<<dim3(16, 8, 16), 256, 0, stream>>>(q_ws, kv_ws, vt_ws, q_ws);
    // output projection + fp32 bias: [65536,512](bf16) x [512,512] -> fp32 out
    gemm_bt<false, true><<<dim3(1024), 512, 0, stream>>>(
        (const void*)q_ws, WoT, (void*)out, bo, 65536, 512, 512, 1);
}

// Round 4
// 419.276 us; speedup vs baseline: 1.1487x; 1.0130x over previous
//
#include <hip/hip_runtime.h>

typedef unsigned short u16;
typedef unsigned int u32;
typedef __bf16 bf16_t;
typedef bf16_t bf16x8 __attribute__((ext_vector_type(8)));
typedef float floatx4 __attribute__((ext_vector_type(4)));

__device__ __forceinline__ float bf2f(u16 h) {
    union { unsigned u; float f; } v;
    v.u = ((unsigned)h) << 16;
    return v.f;
}

__device__ __forceinline__ u16 f2bf(float f) {
    union { float f; unsigned u; } v;
    v.f = f;
    unsigned r = v.u + 0x7fffu + ((v.u >> 16) & 1u);
    return (u16)(r >> 16);
}

// async global->LDS, 16B per lane. LDS dest = uniform base + lane*16 (HW rule).
typedef __attribute__((address_space(1))) const u32 gu32;
typedef __attribute__((address_space(3))) u32 lu32;
__device__ __forceinline__ void gload16(const void* g, void* l) {
    __builtin_amdgcn_global_load_lds((gu32*)g, (lu32*)l, 16, 0, 0);
}

// ---------------------------------------------------------------------------
// Weight transposes: fp32 in -> bf16 transposed out (tiny, L2-resident)
// ---------------------------------------------------------------------------
__global__ void transpose_one(const float* __restrict__ W, u16* __restrict__ Wt,
                              int K, int N) {
    int idx = blockIdx.x * 256 + threadIdx.x;
    if (idx >= K * N) return;
    int nrow = idx / K;
    int k = idx - nrow * K;
    Wt[idx] = f2bf(W[k * N + nrow]);   // Wt[n][k] = W[k][n]
}

// WkvT [1024][768]: rows 0..511 = Wk^T, rows 512..1023 = Wv^T
__global__ void transpose_kv(const float* __restrict__ Wk, const float* __restrict__ Wv,
                             u16* __restrict__ Wt) {
    int idx = blockIdx.x * 256 + threadIdx.x;
    if (idx >= 1024 * 768) return;
    int nrow = idx / 768;
    int k = idx - nrow * 768;
    Wt[idx] = f2bf((nrow < 512) ? Wk[k * 512 + nrow] : Wv[k * 512 + (nrow - 512)]);
}

// V^T for attention: vt[((n*8+h)*64+s)*96 + c] = v[n][c][h][s], zero c>=77.
__global__ void transpose_v(const u16* __restrict__ kv, u16* __restrict__ vt) {
    int idx = blockIdx.x * 256 + threadIdx.x;
    if (idx >= 16 * 8 * 64 * 96) return;
    int c  = idx % 96;
    int t1 = idx / 96;
    int s  = t1 & 63;
    int t2 = t1 >> 6;
    int h  = t2 & 7;
    int n  = t2 >> 3;
    u16 val = 0;
    if (c < 77) val = kv[((long)(n * 77 + c)) * 1024 + 512 + h * 64 + s];
    vt[idx] = val;
}

// ---------------------------------------------------------------------------
// GEMM: C[M,N] = A[M,K] * Bt[N,K]^T (+bias), bf16 MFMA, fp32 accum.
// TM=128 x TN=256, 512 threads (8 waves, 2M x 4N). Double-buffered LDS with
// COUNTED vmcnt pipeline: stage(t+1) issued, then s_waitcnt vmcnt(NL) waits
// only for tile t's loads -- t+1's loads stay in flight across both raw
// s_barriers and the whole compute phase (T4; __syncthreads would drain to 0).
// Row guards are CLAMPS so every wave issues a static load count (vmcnt
// correctness). XOR chunk swizzles (source-side + read-side, linear LDS dest)
// kill the 8-way bank conflicts of 128B-row (fp32 A) and 64B-row (bf16) tiles.
// Requires: gridDim.x % 8 == 0, K % 32 == 0, N % 256 == 0.
// ---------------------------------------------------------------------------
#define TM 128
#define TN 256
#define TK 32

template <bool A_F32, bool OUT_F32>
__global__ __launch_bounds__(512, 4) void gemm_bt(
    const void* __restrict__ A_, const u16* __restrict__ Bt,
    void* __restrict__ C_, const float* __restrict__ bias,
    int M, int K, int N, int ntl2)   // ntl2 = log2(# N tiles)
{
    constexpr int AB = A_F32 ? TM * TK * 4 : TM * TK * 2;   // A tile bytes
    constexpr int BB = TN * TK * 2;                          // B tile bytes
    __shared__ __align__(16) char smem[2 * (AB + BB)];

    const int tid  = threadIdx.x;
    const int lane = tid & 63;
    const int wave = tid >> 6;          // 0..7
    const int quad = lane >> 4;
    const int l16  = lane & 15;
    const int wm   = (wave & 1) * 64;   // 2 M-waves
    const int wn   = (wave >> 1) * 64;  // 4 N-waves -> covers 256

    // XCD-aware bijective swizzle (nwg % 8 == 0), N-tile fastest within XCD.
    const int nwg = gridDim.x;
    const int wg  = blockIdx.x;
    const int t   = (wg & 7) * (nwg >> 3) + (wg >> 3);
    const long bm = (long)(t >> ntl2) * TM;
    const long bn = (long)(t & ((1 << ntl2) - 1)) * TN;

    const float* Af = (const float*)A_;
    const u16*   Ab = (const u16*)A_;
    const long   Mm1 = (long)M - 1;

    floatx4 acc[4][4] = {};

    // Per-wave loads per stage: B=2, A=(A_F32?2:1). Static (clamped rows).
    auto stage = [&](int b, int k0) {
        char* Abase = smem + b * (AB + BB);
        u16*  Bb    = (u16*)(Abase + AB);
        // ---- B: 256x32 bf16 = 1024 x 16B chunks, 2/thread, linear LDS.
        //      Source-side swizzle: physical chunk pc holds logical chunk
        //      pc ^ ((row>>1)&3); read side applies the same XOR.
        #pragma unroll
        for (int p = 0; p < 2; ++p) {
            int ch  = p * 512 + tid;
            int row = ch >> 2;
            int pc  = (ch & 3) ^ ((row >> 1) & 3);
            gload16(Bt + (bn + row) * K + k0 + pc * 8,
                    Bb + (p * 512 + wave * 64) * 8);
        }
        if (A_F32) {
            // ---- A fp32: 128x32 = 1024 chunks, 2/thread; XOR src swizzle ----
            #pragma unroll
            for (int p = 0; p < 2; ++p) {
                int ch  = p * 512 + tid;
                int row = ch >> 3;
                int pcs = (ch & 7) ^ (row & 7);
                long gr = bm + row; if (gr > Mm1) gr = Mm1;   // clamp, not skip
                gload16(Af + gr * K + k0 + pcs * 4,
                        (float*)Abase + (p * 512 + wave * 64) * 4);
            }
        } else {
            // ---- A bf16: 128x32 = 512 chunks, 1/thread; 64B-row swizzle ----
            int row = tid >> 2;
            int pc  = (tid & 3) ^ ((row >> 1) & 3);
            long gr = bm + row; if (gr > Mm1) gr = Mm1;       // clamp, not skip
            gload16(Ab + gr * K + k0 + pc * 8,
                    (u16*)Abase + (wave * 64) * 8);
        }
    };

    const int nk = K / TK;
    stage(0, 0);                       // tile 0 in flight (4 or 3 per wave)

    for (int tt = 0; tt < nk; ++tt) {
        const int cb = tt & 1;
        if (tt + 1 < nk) {
            stage(cb ^ 1, (tt + 1) * TK);      // tile t+1 loads join the queue
            if (A_F32) asm volatile("s_waitcnt vmcnt(4)" ::: "memory");
            else       asm volatile("s_waitcnt vmcnt(3)" ::: "memory");
        } else {
            asm volatile("s_waitcnt vmcnt(0)" ::: "memory");
        }
        __builtin_amdgcn_s_barrier();          // all waves: tile t resident
        __builtin_amdgcn_sched_barrier(0);     // keep ds_reads below barrier

        const char* Abase = smem + cb * (AB + BB);
        const u16*  Bb    = (const u16*)(Abase + AB);

        bf16x8 af[4], bfr[4];
        #pragma unroll
        for (int i = 0; i < 4; ++i) {
            int row = wm + i * 16 + l16;
            if (A_F32) {
                const char* arow = Abase + (size_t)row * 128;
                int x = row & 7;
                float4 f0 = *(const float4*)(arow + (((quad * 2)     ^ x) * 16));
                float4 f1 = *(const float4*)(arow + (((quad * 2 + 1) ^ x) * 16));
                union { bf16_t h[8]; bf16x8 v; } pk;
                pk.h[0] = (bf16_t)f0.x; pk.h[1] = (bf16_t)f0.y;
                pk.h[2] = (bf16_t)f0.z; pk.h[3] = (bf16_t)f0.w;
                pk.h[4] = (bf16_t)f1.x; pk.h[5] = (bf16_t)f1.y;
                pk.h[6] = (bf16_t)f1.z; pk.h[7] = (bf16_t)f1.w;
                af[i] = pk.v;
            } else {
                int pcs = quad ^ ((row >> 1) & 3);
                af[i] = *(const bf16x8*)((const u16*)Abase + row * 32 + pcs * 8);
            }
        }
        #pragma unroll
        for (int j = 0; j < 4; ++j) {
            int row = wn + j * 16 + l16;
            int pcs = quad ^ ((row >> 1) & 3);
            bfr[j] = *(const bf16x8*)(Bb + row * 32 + pcs * 8);
        }
        #pragma unroll
        for (int i = 0; i < 4; ++i)
            #pragma unroll
            for (int j = 0; j < 4; ++j)
                acc[i][j] = __builtin_amdgcn_mfma_f32_16x16x32_bf16(
                    af[i], bfr[j], acc[i][j], 0, 0, 0);

        __builtin_amdgcn_s_barrier();   // all reads of buf cb done -> reusable
    }

    #pragma unroll
    for (int i = 0; i < 4; ++i) {
        #pragma unroll
        for (int r = 0; r < 4; ++r) {
            long row = bm + wm + i * 16 + quad * 4 + r;
            if (row >= M) continue;
            #pragma unroll
            for (int j = 0; j < 4; ++j) {
                long col = bn + wn + j * 16 + l16;
                float val = acc[i][j][r];
                if (bias) val += bias[col];
                if (OUT_F32) ((float*)C_)[row * N + col] = val;
                else         ((u16*)C_)[row * N + col] = f2bf(val);
            }
        }
    }
}

// ---------------------------------------------------------------------------
// Fused attention v3 (unchanged this round). Grid (qc=16, h=8, n=16).
// ---------------------------------------------------------------------------
__global__ __launch_bounds__(256) void attn_kernel(
    const u16* __restrict__ qb,   // [N, 4096, 512] bf16
    const u16* __restrict__ kvb,  // [N*77, 1024] bf16 (cols 0..511 k)
    const u16* __restrict__ vt,   // [(n*8+h)*64+s][96] bf16, zero c>=77
    u16* __restrict__ ob)         // [N, 4096, 512] bf16
{
    const int QL = 4096, HS = 512;
    const int q0 = blockIdx.x * 256;
    const int h  = blockIdx.y;
    const int n  = blockIdx.z;

    __shared__ u16 sQP[128 * 104];  // q tile (stride 72) / P (stride 104)
    __shared__ u16 ks [80 * 72];    // k [c][s], c zero-padded to 80
    __shared__ u16 vts[64 * 104];   // V^T [s][c]

    const int tid  = threadIdx.x;
    const int lane = tid & 63;
    const int wave = tid >> 6;
    const int quad = lane >> 4;
    const int l16  = lane & 15;
    const int wm   = wave * 32;

    const u16* kbase = kvb + (long)n * 77 * 1024 + h * 64;
    for (int v = tid; v < 640; v += 256) {
        int c = v >> 3, g = (v & 7) * 8;
        uint4 val = make_uint4(0, 0, 0, 0);
        if (c < 77) val = *(const uint4*)(kbase + (long)c * 1024 + g);
        *(uint4*)(&ks[c * 72 + g]) = val;
    }
    const u16* vtbase = vt + (long)((n * 8 + h) * 64) * 96;
    for (int v = tid; v < 768; v += 256) {           // 64 rows x 12 uint4
        int r = v / 12, c8 = v - r * 12;
        *(uint4*)(&vts[r * 104 + c8 * 8]) = *(const uint4*)(vtbase + v * 8);
    }
    __syncthreads();

    const bool v4ok = (l16 < 13);

    for (int it = 0; it < 2; ++it) {
        const long qrow0 = (long)q0 + it * 128;
        const u16* qbase = qb + ((long)n * QL + qrow0) * HS + h * 64;
        u16*       obase = ob + ((long)n * QL + qrow0) * HS + h * 64;

        #pragma unroll
        for (int p = 0; p < 4; ++p) {
            int v = tid + p * 256;
            int r = v >> 3, g = (v & 7) * 8;
            *(uint4*)(&sQP[r * 72 + g]) = *(const uint4*)(qbase + (long)r * HS + g);
        }
        __syncthreads();

        floatx4 accS[2][5] = {};
        #pragma unroll
        for (int kk = 0; kk < 2; ++kk) {
            bf16x8 aq[2], bk[5];
            #pragma unroll
            for (int t = 0; t < 2; ++t)
                aq[t] = *(const bf16x8*)(&sQP[(wm + t * 16 + l16) * 72 + kk * 32 + quad * 8]);
            #pragma unroll
            for (int j = 0; j < 5; ++j)
                bk[j] = *(const bf16x8*)(&ks[(j * 16 + l16) * 72 + kk * 32 + quad * 8]);
            #pragma unroll
            for (int t = 0; t < 2; ++t)
                #pragma unroll
                for (int j = 0; j < 5; ++j)
                    accS[t][j] = __builtin_amdgcn_mfma_f32_16x16x32_bf16(
                        aq[t], bk[j], accS[t][j], 0, 0, 0);
        }

        float pw[2][5][4];
        #pragma unroll
        for (int t = 0; t < 2; ++t) {
            #pragma unroll
            for (int r = 0; r < 4; ++r) {
                float v0 = accS[t][0][r] * 0.125f;
                float v1 = accS[t][1][r] * 0.125f;
                float v2 = accS[t][2][r] * 0.125f;
                float v3 = accS[t][3][r] * 0.125f;
                float v4 = v4ok ? accS[t][4][r] * 0.125f : -1e30f;
                float mx = fmaxf(fmaxf(fmaxf(v0, v1), fmaxf(v2, v3)), v4);
                mx = fmaxf(mx, __shfl_xor(mx, 1));
                mx = fmaxf(mx, __shfl_xor(mx, 2));
                mx = fmaxf(mx, __shfl_xor(mx, 4));
                mx = fmaxf(mx, __shfl_xor(mx, 8));
                float e0 = __expf(v0 - mx), e1 = __expf(v1 - mx);
                float e2 = __expf(v2 - mx), e3 = __expf(v3 - mx);
                float e4 = __expf(v4 - mx);
                float sum = e0 + e1 + e2 + e3 + e4;
                sum += __shfl_xor(sum, 1);
                sum += __shfl_xor(sum, 2);
                sum += __shfl_xor(sum, 4);
                sum += __shfl_xor(sum, 8);
                float inv = 1.f / sum;
                pw[t][0][r] = e0 * inv; pw[t][1][r] = e1 * inv;
                pw[t][2][r] = e2 * inv; pw[t][3][r] = e3 * inv;
                pw[t][4][r] = e4 * inv;
            }
        }
        __syncthreads();

        #pragma unroll
        for (int t = 0; t < 2; ++t) {
            #pragma unroll
            for (int r = 0; r < 4; ++r) {
                int row = wm + t * 16 + quad * 4 + r;
                #pragma unroll
                for (int j = 0; j < 5; ++j)
                    sQP[row * 104 + j * 16 + l16] = f2bf(pw[t][j][r]);
                sQP[row * 104 + 80 + l16] = 0;
            }
        }
        __syncthreads();

        floatx4 accO[2][4] = {};
        #pragma unroll
        for (int kk = 0; kk < 3; ++kk) {
            bf16x8 aw[2], bv[4];
            #pragma unroll
            for (int t = 0; t < 2; ++t)
                aw[t] = *(const bf16x8*)(&sQP[(wm + t * 16 + l16) * 104 + kk * 32 + quad * 8]);
            #pragma unroll
            for (int j = 0; j < 4; ++j)
                bv[j] = *(const bf16x8*)(&vts[(j * 16 + l16) * 104 + kk * 32 + quad * 8]);
            #pragma unroll
            for (int t = 0; t < 2; ++t)
                #pragma unroll
                for (int j = 0; j < 4; ++j)
                    accO[t][j] = __builtin_amdgcn_mfma_f32_16x16x32_bf16(
                        aw[t], bv[j], accO[t][j], 0, 0, 0);
        }

        #pragma unroll
        for (int t = 0; t < 2; ++t)
            #pragma unroll
            for (int j = 0; j < 4; ++j)
                #pragma unroll
                for (int r = 0; r < 4; ++r) {
                    int row = wm + t * 16 + quad * 4 + r;
                    obase[(long)row * HS + j * 16 + l16] = f2bf(accO[t][j][r]);
                }
        __syncthreads();
    }
}

// ---------------------------------------------------------------------------
extern "C" void kernel_launch(void* const* d_in, const int* in_sizes, int n_in,
                              void* d_out, int out_size, void* d_ws, size_t ws_size,
                              hipStream_t stream) {
    const float* query   = (const float*)d_in[0];  // [16,4096,512] fp32
    const float* context = (const float*)d_in[1];  // [16,77,768]   fp32
    const float* Wq      = (const float*)d_in[2];  // [512,512]     fp32
    const float* Wk      = (const float*)d_in[3];  // [768,512]     fp32
    const float* Wv      = (const float*)d_in[4];  // [768,512]     fp32
    const float* Wo      = (const float*)d_in[5];  // [512,512]     fp32
    const float* bo      = (const float*)d_in[6];  // [512]         fp32
    float* out = (float*)d_out;                    // [16,4096,512] fp32

    // workspace layout (u16 elements)
    u16* q_ws  = (u16*)d_ws;            // 16*4096*512 (also attn out, in-place)
    u16* kv_ws = q_ws + 33554432;       // 1232*1024
    u16* WqT   = kv_ws + 1261568;       // 512*512
    u16* WkvT  = WqT + 262144;          // 1024*768
    u16* WoT   = WkvT + 786432;         // 512*512
    u16* vt_ws = WkvT;                  // reuse (WkvT dead after kv-proj)

    transpose_one<<<(512 * 512 + 255) / 256, 256, 0, stream>>>(Wq, WqT, 512, 512);
    transpose_kv<<<(1024 * 768 + 255) / 256, 256, 0, stream>>>(Wk, Wv, WkvT);
    transpose_one<<<(512 * 512 + 255) / 256, 256, 0, stream>>>(Wo, WoT, 512, 512);

    // q projection: [65536,512](fp32) x [512,512] -> bf16 ws
    // 512 M-tiles x 2 N-tiles = 1024 wgs (div 8), ntl2 = 1
    gemm_bt<true, false><<<dim3(1024), 512, 0, stream>>>(
        (const void*)query, WqT, (void*)q_ws, nullptr, 65536, 512, 512, 1);
    // k,v projection fused: [1232,768](fp32) x [768,1024] -> bf16 ws
    // 10 M-tiles x 4 N-tiles = 40 wgs (div 8), ntl2 = 2
    gemm_bt<true, false><<<dim3(40), 512, 0, stream>>>(
        (const void*)context, WkvT, (void*)kv_ws, nullptr, 1232, 768, 1024, 2);
    // V^T scatter (overwrites WkvT region, which is now dead)
    transpose_v<<<(16 * 8 * 64 * 96 + 255) / 256, 256, 0, stream>>>(kv_ws, vt_ws);
    // attention, in-place on q_ws (bf16)
    attn_kernel<<<dim3(16, 8, 16), 256, 0, stream>>>(q_ws, kv_ws, vt_ws, q_ws);
    // output projection + fp32 bias: [65536,512](bf16) x [512,512] -> fp32 out
    gemm_bt<false, true><<<dim3(1024), 512, 0, stream>>>(
        (const void*)q_ws, WoT, (void*)out, bo, 65536, 512, 512, 1);
}